// Round 5
// baseline (1621.514 us; speedup 1.0000x reference)
//
#include <hip/hip_runtime.h>
#include <stdint.h>
#include <math.h>

// ---------------------------------------------------------------------------
// Generator_44555990728950. B=4096 molecules, N=32 nodes (chain), H=128,
// 16 GAT layers. All 32 nodes of a molecule are identical through the GAT
// stack (broadcast init + attention weights sum to 1 over identical
// neighbors), so: layer = relu(x + x@W + b), one class per molecule.
// R11: k-split WAVE PAIRS in 128-thread blocks + R10's software pipeline.
//   R10 post-mortem: 143 cyc/iter at 1 wave/SIMD -- ILP pipeline alone can't
//   hide the rest (VGPR=108: compiler kept ~6 loads in flight). Need TLP
//   without extra W traffic: block = 2 waves = 1 pair, 4 mols; wave wh does
//   K-half [64wh,64wh+64) for all 4 mols; partials merged via LDS with 2
//   PAIR-LOCAL barriers/layer. 1024 blocks x 2 waves = 2048 waves =
//   2 waves/SIMD; 4 independent blocks/CU overlap each other's barriers
//   (unlike R7's whole-block lockstep). Per-CU: VMEM ~29us, VALU ~34us.
// Deterministic pipeline fp64; JAX partitionable threefry bit-exact; outputs
// fp32. Per-node sampling / edge heads same math as R9/R10.
// ---------------------------------------------------------------------------

struct U2 { uint32_t a, b; };

// Threefry-2x32, 20 rounds, exactly as jax._src.prng
__device__ __forceinline__ U2 threefry(uint32_t k0, uint32_t k1, uint32_t x0, uint32_t x1) {
  const uint32_t ks2 = k0 ^ k1 ^ 0x1BD11BDAu;
#define TFR(r) { x0 += x1; x1 = (x1 << (r)) | (x1 >> (32 - (r))); x1 ^= x0; }
  x0 += k0;  x1 += k1;
  TFR(13) TFR(15) TFR(26) TFR(6)
  x0 += k1;  x1 += ks2 + 1u;
  TFR(17) TFR(29) TFR(16) TFR(24)
  x0 += ks2; x1 += k0 + 2u;
  TFR(13) TFR(15) TFR(26) TFR(6)
  x0 += k0;  x1 += k1 + 3u;
  TFR(17) TFR(29) TFR(16) TFR(24)
  x0 += k1;  x1 += ks2 + 4u;
  TFR(13) TFR(15) TFR(26) TFR(6)
  x0 += ks2; x1 += k0 + 5u;
#undef TFR
  U2 r; r.a = x0; r.b = x1; return r;
}

// partitionable random_bits, 32-bit: counter = flat index; fold o1^o2
__device__ __forceinline__ uint32_t pbits(uint32_t k0, uint32_t k1, uint32_t ctr) {
  U2 r = threefry(k0, k1, 0u, ctr);
  return r.a ^ r.b;
}

__device__ __forceinline__ float bits_to_unit(uint32_t bits) {
  return __uint_as_float((bits >> 9) | 0x3f800000u) - 1.0f;  // [0,1)
}

// f32 uniform(1e-6, 1-1e-6) -> gumbel, exactly jax's f32 path
__device__ __forceinline__ float jgumbel(uint32_t k0, uint32_t k1, uint32_t ctr) {
  const float minv = 1e-6f;
  const float maxv = (float)(1.0 - 1e-6);
  const float span = maxv - minv;
  float f = bits_to_unit(pbits(k0, k1, ctr));
  float u = fmaxf(minv, __fadd_rn(__fmul_rn(f, span), minv));
  return -logf(-logf(u));
}

extern "C" __global__ void __launch_bounds__(128, 2)
gen_kernel(const float* __restrict__ noise,
           const float* __restrict__ w1,
           const float* __restrict__ b1,
           const float* __restrict__ gat_w,
           const float* __restrict__ gat_b,
           const float* __restrict__ w_atom,
           const float* __restrict__ b_atom,
           const float* __restrict__ w_hyb,
           const float* __restrict__ b_hyb,
           const float* __restrict__ w_deg,
           const float* __restrict__ b_deg,
           const float* __restrict__ w_chg,
           const float* __restrict__ b_chg,
           const float* __restrict__ w_arom,
           const float* __restrict__ b_arom,
           const float* __restrict__ w_eex,
           const float* __restrict__ b_eex,
           const float* __restrict__ w_ety,
           const float* __restrict__ b_ety,
           float* __restrict__ out)
{
  // Block = 2 waves = 1 pair = 4 molecules.
  // x layout: sXa[k] = {x_m0[k], x_m1[k]}, sXb[k] = {x_m2[k], x_m3[k]}
  // -> k-loop reads are uniform-address ds_read_b128 broadcasts.
  __shared__ __align__(16) double sXa[128][2];   // 2 KB
  __shared__ __align__(16) double sXb[128][2];   // 2 KB
  __shared__ __align__(16) double sRed[2][64][4];// partial exchange, 4 KB
  __shared__ double sScr[4][16];                 // head logits, 512 B
  __shared__ float  sNF[4][32][17];              // node features, 8.7 KB
  __shared__ double sLP[4][64];                  // lp scratch, 2 KB

  const int t       = threadIdx.x;
  const int wh      = t >> 6;          // wave in pair = K-half = mol-pair owner
  const int ln      = t & 63;
  const int molBase = blockIdx.x * 4;
  const int c0      = ln << 1;         // lane's two columns

  // ---------------- stage noise: wave wh stages mols 2wh, 2wh+1
  {
    const int mA = molBase + 2 * wh;
    const float2 na = *(const float2*)(noise + (size_t)mA * 128 + c0);
    const float2 nb = *(const float2*)(noise + (size_t)(mA + 1) * 128 + c0);
    double* dst = wh ? &sXb[0][0] : &sXa[0][0];
    double2 v;
    v.x = (double)na.x; v.y = (double)nb.x; *(double2*)(dst + (size_t)c0 * 2)       = v;
    v.x = (double)na.y; v.y = (double)nb.y; *(double2*)(dst + (size_t)(c0 + 1) * 2) = v;
  }
  __syncthreads();

  double2 xrA, xrB;   // residual: x[c0],x[c0+1] for own mols (2wh, 2wh+1)

  // ---------------- 17 unified layers:
  //   l==0 : x = relu(noise @ w1 + b1)
  //   l>=1 : x = relu(x + x@W_l + b_l)
  // Wave wh accumulates K in [64wh, 64wh+64); 2-stage SW pipeline, 8-iter chunks.
  #pragma unroll 1
  for (int l = 0; l < 17; ++l) {
    const float* __restrict__ W  = (l == 0) ? w1 : (gat_w + (((size_t)(l - 1)) << 14));
    const float* __restrict__ bp = (l == 0) ? b1 : (gat_b + ((l - 1) << 7));
    const int kb = wh << 6;

    double p0x = 0.0, p0y = 0.0, p1x = 0.0, p1y = 0.0;
    double p2x = 0.0, p2y = 0.0, p3x = 0.0, p3y = 0.0;

    float2  wA[8];  double2 xaA[8], xbA[8];
    float2  wB[8];  double2 xaB[8], xbB[8];

    // prologue: chunk 0 -> buffer A
    #pragma unroll
    for (int j = 0; j < 8; ++j) {
      wA[j]  = *(const float2*)(W + ((kb + j) << 7) + c0);
      xaA[j] = *(const double2*)&sXa[kb + j][0];
      xbA[j] = *(const double2*)&sXb[kb + j][0];
    }

    #pragma unroll
    for (int ch = 0; ch < 8; ++ch) {
      const int nb_ = kb + ((ch + 1) << 3);          // next chunk base
      if ((ch & 1) == 0) {
        if (ch < 7) {
          #pragma unroll
          for (int j = 0; j < 8; ++j) {
            wB[j]  = *(const float2*)(W + ((nb_ + j) << 7) + c0);
            xaB[j] = *(const double2*)&sXa[nb_ + j][0];
            xbB[j] = *(const double2*)&sXb[nb_ + j][0];
          }
        }
        #pragma unroll
        for (int j = 0; j < 8; ++j) {
          const double wx = (double)wA[j].x, wy = (double)wA[j].y;
          p0x = fma(xaA[j].x, wx, p0x); p0y = fma(xaA[j].x, wy, p0y);
          p1x = fma(xaA[j].y, wx, p1x); p1y = fma(xaA[j].y, wy, p1y);
          p2x = fma(xbA[j].x, wx, p2x); p2y = fma(xbA[j].x, wy, p2y);
          p3x = fma(xbA[j].y, wx, p3x); p3y = fma(xbA[j].y, wy, p3y);
        }
      } else {
        if (ch < 7) {
          #pragma unroll
          for (int j = 0; j < 8; ++j) {
            wA[j]  = *(const float2*)(W + ((nb_ + j) << 7) + c0);
            xaA[j] = *(const double2*)&sXa[nb_ + j][0];
            xbA[j] = *(const double2*)&sXb[nb_ + j][0];
          }
        }
        #pragma unroll
        for (int j = 0; j < 8; ++j) {
          const double wx = (double)wB[j].x, wy = (double)wB[j].y;
          p0x = fma(xaB[j].x, wx, p0x); p0y = fma(xaB[j].x, wy, p0y);
          p1x = fma(xaB[j].y, wx, p1x); p1y = fma(xaB[j].y, wy, p1y);
          p2x = fma(xbB[j].x, wx, p2x); p2y = fma(xbB[j].x, wy, p2y);
          p3x = fma(xbB[j].y, wx, p3x); p3y = fma(xbB[j].y, wy, p3y);
        }
      }
    }

    // exchange: write partials for the SIBLING's mols, read ours back
    {
      double2 v;
      if (wh == 0) {
        v.x = p2x; v.y = p2y; *(double2*)&sRed[0][ln][0] = v;
        v.x = p3x; v.y = p3y; *(double2*)&sRed[0][ln][2] = v;
      } else {
        v.x = p0x; v.y = p0y; *(double2*)&sRed[1][ln][0] = v;
        v.x = p1x; v.y = p1y; *(double2*)&sRed[1][ln][2] = v;
      }
    }
    __syncthreads();
    {
      const double2 qa = *(const double2*)&sRed[wh ^ 1][ln][0];
      const double2 qb = *(const double2*)&sRed[wh ^ 1][ln][2];
      const double ownAx = (wh ? p2x : p0x) + qa.x;
      const double ownAy = (wh ? p2y : p0y) + qa.y;
      const double ownBx = (wh ? p3x : p1x) + qb.x;
      const double ownBy = (wh ? p3y : p1y) + qb.y;
      const float2 bb = *(const float2*)(bp + c0);
      const double bx = (double)bb.x, by = (double)bb.y;
      double nAx, nAy, nBx, nBy;
      if (l == 0) {
        nAx = fmax(ownAx + bx, 0.0); nAy = fmax(ownAy + by, 0.0);
        nBx = fmax(ownBx + bx, 0.0); nBy = fmax(ownBy + by, 0.0);
      } else {
        nAx = fmax(xrA.x + ownAx + bx, 0.0); nAy = fmax(xrA.y + ownAy + by, 0.0);
        nBx = fmax(xrB.x + ownBx + bx, 0.0); nBy = fmax(xrB.y + ownBy + by, 0.0);
      }
      xrA.x = nAx; xrA.y = nAy; xrB.x = nBx; xrB.y = nBy;
      double* dst = wh ? &sXb[0][0] : &sXa[0][0];
      double2 v;
      v.x = nAx; v.y = nBx; *(double2*)(dst + (size_t)c0 * 2)       = v;
      v.x = nAy; v.y = nBy; *(double2*)(dst + (size_t)(c0 + 1) * 2) = v;
    }
    __syncthreads();
  }

  // ---------------- phase A: head logits; each wave: its 2 mols x 16 heads
  if (ln < 32) {
    const int mloc = 2 * wh + (ln >> 4);   // 0..3
    const int h    = ln & 15;
    const double* xsrc = (mloc < 2) ? &sXa[0][mloc] : &sXb[0][mloc - 2];
    const float* wp; int stride; double bias;
    if (h < 10)       { wp = w_atom + h;        stride = 10; bias = (double)b_atom[h]; }
    else if (h < 13)  { wp = w_hyb + (h - 10);  stride = 3;  bias = (double)b_hyb[h - 10]; }
    else if (h == 13) { wp = w_deg;             stride = 1;  bias = (double)b_deg[0]; }
    else if (h == 14) { wp = w_chg;             stride = 1;  bias = (double)b_chg[0]; }
    else              { wp = w_arom;            stride = 1;  bias = (double)b_arom[0]; }
    double acc = 0.0;
    for (int c = 0; c < 128; ++c)
      acc = fma(xsrc[(size_t)c * 2], (double)wp[c * stride], acc);
    sScr[mloc][h] = acc + bias;
  }
  __syncthreads();

  // partitionable split(key(42),4): child_i = threefry((0,42),(0,i))
  const U2 k0p = threefry(0u, 42u, 0u, 0u);
  const U2 k1p = threefry(0u, 42u, 0u, 1u);
  const U2 k2p = threefry(0u, 42u, 0u, 2u);
  const U2 k3p = threefry(0u, 42u, 0u, 3u);

  // ---------------- phase B: per-node sampling, 128 threads = 4 mols x 32 nodes
  {
    const int mloc = t >> 5;
    const int n    = t & 31;
    const int mol  = molBase + mloc;
    const double* scr = sScr[mloc];       // same logits for every node

    double m = scr[0];
    #pragma unroll
    for (int a = 1; a < 10; ++a) m = fmax(m, scr[a]);
    double lsum = 0.0;
    #pragma unroll
    for (int a = 0; a < 10; ++a) lsum += exp(scr[a] - m);
    const double lse = log(lsum);
    const uint32_t abase = ((uint32_t)mol * 32u + (uint32_t)n) * 10u;
    int asel = 0; double abest = 0.0;
    #pragma unroll
    for (int a = 0; a < 10; ++a) {
      const double g = (double)jgumbel(k0p.a, k0p.b, abase + (uint32_t)a);
      const double sc = scr[a] + g;
      if (a == 0 || sc > abest) { abest = sc; asel = a; }
    }
    sLP[mloc][n] = (scr[asel] - m) - lse;

    double m2 = fmax(fmax(scr[10], scr[11]), scr[12]);
    double ls2 = exp(scr[10] - m2) + exp(scr[11] - m2) + exp(scr[12] - m2);
    const double lse2 = log(ls2);
    const uint32_t hbase = ((uint32_t)mol * 32u + (uint32_t)n) * 3u;
    int hsel = 0; double hbest = 0.0;
    #pragma unroll
    for (int j = 0; j < 3; ++j) {
      const double g = (double)jgumbel(k1p.a, k1p.b, hbase + (uint32_t)j);
      const double sc = scr[10 + j] + g;
      if (j == 0 || sc > hbest) { hbest = sc; hsel = j; }
    }
    sLP[mloc][32 + n] = (scr[10 + hsel] - m2) - lse2;

    const double deg = 1.0 / (1.0 + exp(-scr[13]));
    const double chg = tanh(scr[14]);
    const double pr  = 1.0 / (1.0 + exp(-scr[15]));
    const uint32_t ridx = (uint32_t)mol * 32u + (uint32_t)n;
    const double uu = (double)bits_to_unit(pbits(k2p.a, k2p.b, ridx));
    const double arom = (uu < pr) ? 1.0 : 0.0;
    const double valt[10] = {4.0/5.0, 3.0/5.0, 2.0/5.0, 1.0/5.0, 4.0/5.0,
                             2.0/5.0, 6.0/5.0, 1.0/5.0, 4.0/5.0, 4.0/5.0};
    double nf[17];
    #pragma unroll
    for (int i = 0; i < 10; ++i) nf[i] = (i == asel) ? 1.0 : 0.0;
    nf[10] = deg; nf[11] = chg;
    #pragma unroll
    for (int j = 0; j < 3; ++j) nf[12 + j] = (j == hsel) ? 1.0 : 0.0;
    nf[15] = arom; nf[16] = valt[asel];

    const size_t o = ((size_t)mol * 32 + n) * 17;
    #pragma unroll
    for (int i = 0; i < 17; ++i) {
      sNF[mloc][n][i] = (float)nf[i];
      out[o + i] = (float)nf[i];
    }
  }
  __syncthreads();

  // ---------------- phase C: lp means + edge heads; 2 rounds x 2 waves = 4 mols
  #pragma unroll 1
  for (int r = 0; r < 2; ++r) {
    const int mloc = 2 * r + wh;
    const int mol  = molBase + mloc;
    if (ln == 62) {
      double sa = 0.0;
      for (int n = 0; n < 32; ++n) sa += sLP[mloc][n];
      out[2228224 + (size_t)mol] = (float)(sa / 32.0);
    } else if (ln == 63) {
      double sh = 0.0;
      for (int n = 0; n < 32; ++n) sh += sLP[mloc][32 + n];
      out[2232320 + (size_t)mol] = (float)(sh / 32.0);
    } else {
      const int e = ln;                       // 0..61
      const int nu_ = (e < 31) ? e : (e - 30);
      const int nv_ = (e < 31) ? (e + 1) : (e - 31);
      double lex = 0.0;
      double lt[4] = {0.0, 0.0, 0.0, 0.0};
      for (int i = 0; i < 17; ++i) {
        const double f = (double)sNF[mloc][nu_][i];
        lex = fma(f, (double)w_eex[i], lex);
        #pragma unroll
        for (int c = 0; c < 4; ++c) lt[c] = fma(f, (double)w_ety[i * 4 + c], lt[c]);
      }
      for (int i = 0; i < 17; ++i) {
        const double f = (double)sNF[mloc][nv_][i];
        lex = fma(f, (double)w_eex[17 + i], lex);
        #pragma unroll
        for (int c = 0; c < 4; ++c) lt[c] = fma(f, (double)w_ety[(17 + i) * 4 + c], lt[c]);
      }
      lex += (double)b_eex[0];
      #pragma unroll
      for (int c = 0; c < 4; ++c) lt[c] += (double)b_ety[c];

      const double pex = 1.0 / (1.0 + exp(-lex));
      out[3252224 + (size_t)mol * 62 + e] = (pex > 0.5) ? 1.f : 0.f;

      const uint32_t tbase = ((uint32_t)mol * 62u + (uint32_t)e) * 4u;
      int tsel = 0; double tbest = 0.0;
      #pragma unroll
      for (int c = 0; c < 4; ++c) {
        const double g = (double)jgumbel(k3p.a, k3p.b, tbase + (uint32_t)c);
        const double sc = lt[c] + g;
        if (c == 0 || sc > tbest) { tbest = sc; tsel = c; }
      }
      const size_t o = 2236416 + ((size_t)mol * 62 + e) * 4;
      #pragma unroll
      for (int c = 0; c < 4; ++c) out[o + c] = (c == tsel) ? 1.f : 0.f;
    }
  }
}

extern "C" void kernel_launch(void* const* d_in, const int* in_sizes, int n_in,
                              void* d_out, int out_size, void* d_ws, size_t ws_size,
                              hipStream_t stream) {
  (void)in_sizes; (void)n_in; (void)out_size; (void)d_ws; (void)ws_size;
  hipLaunchKernelGGL(gen_kernel, dim3(1024), dim3(128), 0, stream,
                     (const float*)d_in[0],  (const float*)d_in[1],
                     (const float*)d_in[2],  (const float*)d_in[3],
                     (const float*)d_in[4],
                     (const float*)d_in[7],  (const float*)d_in[8],
                     (const float*)d_in[9],  (const float*)d_in[10],
                     (const float*)d_in[11], (const float*)d_in[12],
                     (const float*)d_in[13], (const float*)d_in[14],
                     (const float*)d_in[15], (const float*)d_in[16],
                     (const float*)d_in[17], (const float*)d_in[18],
                     (const float*)d_in[19], (const float*)d_in[20],
                     (float*)d_out);
}

// Round 6
// 959.165 us; speedup vs baseline: 1.6905x; 1.6905x over previous
//
#include <hip/hip_runtime.h>
#include <stdint.h>
#include <math.h>

// ---------------------------------------------------------------------------
// Generator_44555990728950. B=4096 molecules, N=32 nodes (chain), H=128,
// 16 GAT layers. All 32 nodes of a molecule are identical through the GAT
// stack (broadcast init + attention weights sum to 1 over identical
// neighbors), so: layer = relu(x + x@W + b), one class per molecule.
// R12: k-split wave pairs inside 256-thread blocks (2 pairs/block).
//   R11 post-mortem: __launch_bounds__(128,2) forced VGPR cap 128 -> the
//   depth-8 pipeline SPILLED to scratch (FETCH 1.84 GB, WRITE 2.5 GB,
//   VALUBusy 3.3%). Same structure, R10's compilation regime: 256-thread
//   blocks, NO min-waves bound (R10: compiler trims pipeline depth instead
//   of spilling; VGPR=108, zero scratch).
//   Block = 2 pairs; pair = 2 waves, 4 mols, wave wh owns K-half
//   [64wh,64wh+64); partials merged via LDS + 2 block barriers/layer.
//   512 blocks = 2 blocks/CU = 8 waves/CU = 2 waves/SIMD (TLP R10 lacked)
//   at unchanged W amortization (4 mols/wave -> per-CU VMEM ~29us).
// Deterministic pipeline fp64; JAX partitionable threefry bit-exact; outputs
// fp32. Per-node sampling / edge heads same math as R9/R10/R11.
// ---------------------------------------------------------------------------

struct U2 { uint32_t a, b; };

// Threefry-2x32, 20 rounds, exactly as jax._src.prng
__device__ __forceinline__ U2 threefry(uint32_t k0, uint32_t k1, uint32_t x0, uint32_t x1) {
  const uint32_t ks2 = k0 ^ k1 ^ 0x1BD11BDAu;
#define TFR(r) { x0 += x1; x1 = (x1 << (r)) | (x1 >> (32 - (r))); x1 ^= x0; }
  x0 += k0;  x1 += k1;
  TFR(13) TFR(15) TFR(26) TFR(6)
  x0 += k1;  x1 += ks2 + 1u;
  TFR(17) TFR(29) TFR(16) TFR(24)
  x0 += ks2; x1 += k0 + 2u;
  TFR(13) TFR(15) TFR(26) TFR(6)
  x0 += k0;  x1 += k1 + 3u;
  TFR(17) TFR(29) TFR(16) TFR(24)
  x0 += k1;  x1 += ks2 + 4u;
  TFR(13) TFR(15) TFR(26) TFR(6)
  x0 += ks2; x1 += k0 + 5u;
#undef TFR
  U2 r; r.a = x0; r.b = x1; return r;
}

// partitionable random_bits, 32-bit: counter = flat index; fold o1^o2
__device__ __forceinline__ uint32_t pbits(uint32_t k0, uint32_t k1, uint32_t ctr) {
  U2 r = threefry(k0, k1, 0u, ctr);
  return r.a ^ r.b;
}

__device__ __forceinline__ float bits_to_unit(uint32_t bits) {
  return __uint_as_float((bits >> 9) | 0x3f800000u) - 1.0f;  // [0,1)
}

// f32 uniform(1e-6, 1-1e-6) -> gumbel, exactly jax's f32 path
__device__ __forceinline__ float jgumbel(uint32_t k0, uint32_t k1, uint32_t ctr) {
  const float minv = 1e-6f;
  const float maxv = (float)(1.0 - 1e-6);
  const float span = maxv - minv;
  float f = bits_to_unit(pbits(k0, k1, ctr));
  float u = fmaxf(minv, __fadd_rn(__fmul_rn(f, span), minv));
  return -logf(-logf(u));
}

extern "C" __global__ void __launch_bounds__(256)
gen_kernel(const float* __restrict__ noise,
           const float* __restrict__ w1,
           const float* __restrict__ b1,
           const float* __restrict__ gat_w,
           const float* __restrict__ gat_b,
           const float* __restrict__ w_atom,
           const float* __restrict__ b_atom,
           const float* __restrict__ w_hyb,
           const float* __restrict__ b_hyb,
           const float* __restrict__ w_deg,
           const float* __restrict__ b_deg,
           const float* __restrict__ w_chg,
           const float* __restrict__ b_chg,
           const float* __restrict__ w_arom,
           const float* __restrict__ b_arom,
           const float* __restrict__ w_eex,
           const float* __restrict__ b_eex,
           const float* __restrict__ w_ety,
           const float* __restrict__ b_ety,
           float* __restrict__ out)
{
  // Block = 2 pairs; pair = 2 waves = 4 molecules.
  // x layout per pair: sXa[k] = {x_m0[k], x_m1[k]}, sXb[k] = {x_m2[k], x_m3[k]}
  // -> k-loop reads are uniform-address ds_read_b128 broadcasts.
  __shared__ __align__(16) double sXa[2][128][2];    // 4 KB
  __shared__ __align__(16) double sXb[2][128][2];    // 4 KB
  __shared__ __align__(16) double sRed[2][2][64][4]; // partial exchange, 8 KB
  __shared__ double sScr[2][4][16];                  // head logits, 1 KB
  __shared__ float  sNF[2][4][32][17];               // node features, 17.4 KB
  __shared__ double sLP[2][4][64];                   // lp scratch, 4 KB

  const int t       = threadIdx.x;
  const int wv      = t >> 6;
  const int ln      = t & 63;
  const int pr      = wv >> 1;         // pair id within block (0,1)
  const int wh      = wv & 1;          // K-half AND mol-subpair owner
  const int molBase = blockIdx.x * 8 + pr * 4;
  const int c0      = ln << 1;         // lane's two columns

  // ---------------- stage noise: wave wh stages mols 2wh, 2wh+1 of its pair
  {
    const int mA = molBase + 2 * wh;
    const float2 na = *(const float2*)(noise + (size_t)mA * 128 + c0);
    const float2 nb = *(const float2*)(noise + (size_t)(mA + 1) * 128 + c0);
    double* dst = wh ? &sXb[pr][0][0] : &sXa[pr][0][0];
    double2 v;
    v.x = (double)na.x; v.y = (double)nb.x; *(double2*)(dst + (size_t)c0 * 2)       = v;
    v.x = (double)na.y; v.y = (double)nb.y; *(double2*)(dst + (size_t)(c0 + 1) * 2) = v;
  }
  __syncthreads();

  double2 xrA, xrB;   // residual: x[c0],x[c0+1] for own mols (2wh, 2wh+1)

  // ---------------- 17 unified layers:
  //   l==0 : x = relu(noise @ w1 + b1)
  //   l>=1 : x = relu(x + x@W_l + b_l)
  // Wave wh accumulates K in [64wh, 64wh+64); 2-stage SW pipeline, 8-iter chunks.
  #pragma unroll 1
  for (int l = 0; l < 17; ++l) {
    const float* __restrict__ W  = (l == 0) ? w1 : (gat_w + (((size_t)(l - 1)) << 14));
    const float* __restrict__ bp = (l == 0) ? b1 : (gat_b + ((l - 1) << 7));
    const int kb = wh << 6;

    double p0x = 0.0, p0y = 0.0, p1x = 0.0, p1y = 0.0;
    double p2x = 0.0, p2y = 0.0, p3x = 0.0, p3y = 0.0;

    float2  wA[8];  double2 xaA[8], xbA[8];
    float2  wB[8];  double2 xaB[8], xbB[8];

    // prologue: chunk 0 -> buffer A
    #pragma unroll
    for (int j = 0; j < 8; ++j) {
      wA[j]  = *(const float2*)(W + ((kb + j) << 7) + c0);
      xaA[j] = *(const double2*)&sXa[pr][kb + j][0];
      xbA[j] = *(const double2*)&sXb[pr][kb + j][0];
    }

    #pragma unroll
    for (int ch = 0; ch < 8; ++ch) {
      const int nb_ = kb + ((ch + 1) << 3);          // next chunk base
      if ((ch & 1) == 0) {
        if (ch < 7) {
          #pragma unroll
          for (int j = 0; j < 8; ++j) {
            wB[j]  = *(const float2*)(W + ((nb_ + j) << 7) + c0);
            xaB[j] = *(const double2*)&sXa[pr][nb_ + j][0];
            xbB[j] = *(const double2*)&sXb[pr][nb_ + j][0];
          }
        }
        #pragma unroll
        for (int j = 0; j < 8; ++j) {
          const double wx = (double)wA[j].x, wy = (double)wA[j].y;
          p0x = fma(xaA[j].x, wx, p0x); p0y = fma(xaA[j].x, wy, p0y);
          p1x = fma(xaA[j].y, wx, p1x); p1y = fma(xaA[j].y, wy, p1y);
          p2x = fma(xbA[j].x, wx, p2x); p2y = fma(xbA[j].x, wy, p2y);
          p3x = fma(xbA[j].y, wx, p3x); p3y = fma(xbA[j].y, wy, p3y);
        }
      } else {
        if (ch < 7) {
          #pragma unroll
          for (int j = 0; j < 8; ++j) {
            wA[j]  = *(const float2*)(W + ((nb_ + j) << 7) + c0);
            xaA[j] = *(const double2*)&sXa[pr][nb_ + j][0];
            xbA[j] = *(const double2*)&sXb[pr][nb_ + j][0];
          }
        }
        #pragma unroll
        for (int j = 0; j < 8; ++j) {
          const double wx = (double)wB[j].x, wy = (double)wB[j].y;
          p0x = fma(xaB[j].x, wx, p0x); p0y = fma(xaB[j].x, wy, p0y);
          p1x = fma(xaB[j].y, wx, p1x); p1y = fma(xaB[j].y, wy, p1y);
          p2x = fma(xbB[j].x, wx, p2x); p2y = fma(xbB[j].x, wy, p2y);
          p3x = fma(xbB[j].y, wx, p3x); p3y = fma(xbB[j].y, wy, p3y);
        }
      }
    }

    // exchange: write partials for the SIBLING's mols, read ours back
    {
      double2 v;
      if (wh == 0) {
        v.x = p2x; v.y = p2y; *(double2*)&sRed[pr][0][ln][0] = v;
        v.x = p3x; v.y = p3y; *(double2*)&sRed[pr][0][ln][2] = v;
      } else {
        v.x = p0x; v.y = p0y; *(double2*)&sRed[pr][1][ln][0] = v;
        v.x = p1x; v.y = p1y; *(double2*)&sRed[pr][1][ln][2] = v;
      }
    }
    __syncthreads();
    {
      const double2 qa = *(const double2*)&sRed[pr][wh ^ 1][ln][0];
      const double2 qb = *(const double2*)&sRed[pr][wh ^ 1][ln][2];
      const double ownAx = (wh ? p2x : p0x) + qa.x;
      const double ownAy = (wh ? p2y : p0y) + qa.y;
      const double ownBx = (wh ? p3x : p1x) + qb.x;
      const double ownBy = (wh ? p3y : p1y) + qb.y;
      const float2 bb = *(const float2*)(bp + c0);
      const double bx = (double)bb.x, by = (double)bb.y;
      double nAx, nAy, nBx, nBy;
      if (l == 0) {
        nAx = fmax(ownAx + bx, 0.0); nAy = fmax(ownAy + by, 0.0);
        nBx = fmax(ownBx + bx, 0.0); nBy = fmax(ownBy + by, 0.0);
      } else {
        nAx = fmax(xrA.x + ownAx + bx, 0.0); nAy = fmax(xrA.y + ownAy + by, 0.0);
        nBx = fmax(xrB.x + ownBx + bx, 0.0); nBy = fmax(xrB.y + ownBy + by, 0.0);
      }
      xrA.x = nAx; xrA.y = nAy; xrB.x = nBx; xrB.y = nBy;
      double* dst = wh ? &sXb[pr][0][0] : &sXa[pr][0][0];
      double2 v;
      v.x = nAx; v.y = nBx; *(double2*)(dst + (size_t)c0 * 2)       = v;
      v.x = nAy; v.y = nBy; *(double2*)(dst + (size_t)(c0 + 1) * 2) = v;
    }
    __syncthreads();
  }

  // ---------------- phase A: head logits; each wave: its 2 mols x 16 heads
  if (ln < 32) {
    const int mloc = 2 * wh + (ln >> 4);   // 0..3 within pair
    const int h    = ln & 15;
    const double* xsrc = (mloc < 2) ? &sXa[pr][0][mloc] : &sXb[pr][0][mloc - 2];
    const float* wp; int stride; double bias;
    if (h < 10)       { wp = w_atom + h;        stride = 10; bias = (double)b_atom[h]; }
    else if (h < 13)  { wp = w_hyb + (h - 10);  stride = 3;  bias = (double)b_hyb[h - 10]; }
    else if (h == 13) { wp = w_deg;             stride = 1;  bias = (double)b_deg[0]; }
    else if (h == 14) { wp = w_chg;             stride = 1;  bias = (double)b_chg[0]; }
    else              { wp = w_arom;            stride = 1;  bias = (double)b_arom[0]; }
    double acc = 0.0;
    for (int c = 0; c < 128; ++c)
      acc = fma(xsrc[(size_t)c * 2], (double)wp[c * stride], acc);
    sScr[pr][mloc][h] = acc + bias;
  }
  __syncthreads();

  // partitionable split(key(42),4): child_i = threefry((0,42),(0,i))
  const U2 k0p = threefry(0u, 42u, 0u, 0u);
  const U2 k1p = threefry(0u, 42u, 0u, 1u);
  const U2 k2p = threefry(0u, 42u, 0u, 2u);
  const U2 k3p = threefry(0u, 42u, 0u, 3u);

  // ---------------- phase B: per-node sampling; per pair 128 thr = 4 mols x 32 nodes
  {
    const int tp   = t & 127;             // thread within pair
    const int mloc = tp >> 5;
    const int n    = tp & 31;
    const int mol  = molBase + mloc;
    const double* scr = sScr[pr][mloc];   // same logits for every node

    double m = scr[0];
    #pragma unroll
    for (int a = 1; a < 10; ++a) m = fmax(m, scr[a]);
    double lsum = 0.0;
    #pragma unroll
    for (int a = 0; a < 10; ++a) lsum += exp(scr[a] - m);
    const double lse = log(lsum);
    const uint32_t abase = ((uint32_t)mol * 32u + (uint32_t)n) * 10u;
    int asel = 0; double abest = 0.0;
    #pragma unroll
    for (int a = 0; a < 10; ++a) {
      const double g = (double)jgumbel(k0p.a, k0p.b, abase + (uint32_t)a);
      const double sc = scr[a] + g;
      if (a == 0 || sc > abest) { abest = sc; asel = a; }
    }
    sLP[pr][mloc][n] = (scr[asel] - m) - lse;

    double m2 = fmax(fmax(scr[10], scr[11]), scr[12]);
    double ls2 = exp(scr[10] - m2) + exp(scr[11] - m2) + exp(scr[12] - m2);
    const double lse2 = log(ls2);
    const uint32_t hbase = ((uint32_t)mol * 32u + (uint32_t)n) * 3u;
    int hsel = 0; double hbest = 0.0;
    #pragma unroll
    for (int j = 0; j < 3; ++j) {
      const double g = (double)jgumbel(k1p.a, k1p.b, hbase + (uint32_t)j);
      const double sc = scr[10 + j] + g;
      if (j == 0 || sc > hbest) { hbest = sc; hsel = j; }
    }
    sLP[pr][mloc][32 + n] = (scr[10 + hsel] - m2) - lse2;

    const double deg = 1.0 / (1.0 + exp(-scr[13]));
    const double chg = tanh(scr[14]);
    const double pr_ = 1.0 / (1.0 + exp(-scr[15]));
    const uint32_t ridx = (uint32_t)mol * 32u + (uint32_t)n;
    const double uu = (double)bits_to_unit(pbits(k2p.a, k2p.b, ridx));
    const double arom = (uu < pr_) ? 1.0 : 0.0;
    const double valt[10] = {4.0/5.0, 3.0/5.0, 2.0/5.0, 1.0/5.0, 4.0/5.0,
                             2.0/5.0, 6.0/5.0, 1.0/5.0, 4.0/5.0, 4.0/5.0};
    double nf[17];
    #pragma unroll
    for (int i = 0; i < 10; ++i) nf[i] = (i == asel) ? 1.0 : 0.0;
    nf[10] = deg; nf[11] = chg;
    #pragma unroll
    for (int j = 0; j < 3; ++j) nf[12 + j] = (j == hsel) ? 1.0 : 0.0;
    nf[15] = arom; nf[16] = valt[asel];

    const size_t o = ((size_t)mol * 32 + n) * 17;
    #pragma unroll
    for (int i = 0; i < 17; ++i) {
      sNF[pr][mloc][n][i] = (float)nf[i];
      out[o + i] = (float)nf[i];
    }
  }
  __syncthreads();

  // ---------------- phase C: lp means + edge heads; 2 rounds x 2 waves per pair
  #pragma unroll 1
  for (int r = 0; r < 2; ++r) {
    const int mloc = 2 * r + wh;
    const int mol  = molBase + mloc;
    if (ln == 62) {
      double sa = 0.0;
      for (int n = 0; n < 32; ++n) sa += sLP[pr][mloc][n];
      out[2228224 + (size_t)mol] = (float)(sa / 32.0);
    } else if (ln == 63) {
      double sh = 0.0;
      for (int n = 0; n < 32; ++n) sh += sLP[pr][mloc][32 + n];
      out[2232320 + (size_t)mol] = (float)(sh / 32.0);
    } else {
      const int e = ln;                       // 0..61
      const int nu_ = (e < 31) ? e : (e - 30);
      const int nv_ = (e < 31) ? (e + 1) : (e - 31);
      double lex = 0.0;
      double lt[4] = {0.0, 0.0, 0.0, 0.0};
      for (int i = 0; i < 17; ++i) {
        const double f = (double)sNF[pr][mloc][nu_][i];
        lex = fma(f, (double)w_eex[i], lex);
        #pragma unroll
        for (int c = 0; c < 4; ++c) lt[c] = fma(f, (double)w_ety[i * 4 + c], lt[c]);
      }
      for (int i = 0; i < 17; ++i) {
        const double f = (double)sNF[pr][mloc][nv_][i];
        lex = fma(f, (double)w_eex[17 + i], lex);
        #pragma unroll
        for (int c = 0; c < 4; ++c) lt[c] = fma(f, (double)w_ety[(17 + i) * 4 + c], lt[c]);
      }
      lex += (double)b_eex[0];
      #pragma unroll
      for (int c = 0; c < 4; ++c) lt[c] += (double)b_ety[c];

      const double pex = 1.0 / (1.0 + exp(-lex));
      out[3252224 + (size_t)mol * 62 + e] = (pex > 0.5) ? 1.f : 0.f;

      const uint32_t tbase = ((uint32_t)mol * 62u + (uint32_t)e) * 4u;
      int tsel = 0; double tbest = 0.0;
      #pragma unroll
      for (int c = 0; c < 4; ++c) {
        const double g = (double)jgumbel(k3p.a, k3p.b, tbase + (uint32_t)c);
        const double sc = lt[c] + g;
        if (c == 0 || sc > tbest) { tbest = sc; tsel = c; }
      }
      const size_t o = 2236416 + ((size_t)mol * 62 + e) * 4;
      #pragma unroll
      for (int c = 0; c < 4; ++c) out[o + c] = (c == tsel) ? 1.f : 0.f;
    }
  }
}

extern "C" void kernel_launch(void* const* d_in, const int* in_sizes, int n_in,
                              void* d_out, int out_size, void* d_ws, size_t ws_size,
                              hipStream_t stream) {
  (void)in_sizes; (void)n_in; (void)out_size; (void)d_ws; (void)ws_size;
  hipLaunchKernelGGL(gen_kernel, dim3(512), dim3(256), 0, stream,
                     (const float*)d_in[0],  (const float*)d_in[1],
                     (const float*)d_in[2],  (const float*)d_in[3],
                     (const float*)d_in[4],
                     (const float*)d_in[7],  (const float*)d_in[8],
                     (const float*)d_in[9],  (const float*)d_in[10],
                     (const float*)d_in[11], (const float*)d_in[12],
                     (const float*)d_in[13], (const float*)d_in[14],
                     (const float*)d_in[15], (const float*)d_in[16],
                     (const float*)d_in[17], (const float*)d_in[18],
                     (const float*)d_in[19], (const float*)d_in[20],
                     (float*)d_out);
}

// Round 7
// 247.135 us; speedup vs baseline: 6.5612x; 3.8811x over previous
//
#include <hip/hip_runtime.h>
#include <stdint.h>
#include <math.h>

// ---------------------------------------------------------------------------
// Generator_44555990728950. B=4096 molecules, N=32 nodes (chain), H=128,
// 16 GAT layers. All 32 nodes of a molecule are identical through the GAT
// stack (broadcast init + attention weights sum to 1 over identical
// neighbors), so: layer = relu(x + x@W + b), one class per molecule.
// R13: M=2 molecules per wave, barrier-free, R10's exact pipeline shape.
//   R11/R12 post-mortem: the k-split variants SPILL (R12: VGPR=256, FETCH
//   620 MB, WRITE 314 MB scratch) -- layer-internal barriers + runtime
//   k-base defeat the allocator. R10's barrier-free/compile-time-base form
//   compiled clean (VGPR=108, zero scratch) but is latency-bound at
//   1 wave/SIMD (143 cyc/iter vs ~30 issue). Fix: SAME code shape, M=2:
//   4096/2 = 2048 waves = 512 blocks = 2 blocks/CU = 2 waves/SIMD TLP,
//   and per-chunk register arrays shrink 80->48 VGPR (more headroom than
//   the proven R10 build). Cost: per-CU W-load pipe ~29-58us (binding);
//   VALU ~36us; DS ~29us.
// Deterministic pipeline fp64; JAX partitionable threefry bit-exact; outputs
// fp32. Per-node sampling / edge heads same math as R9/R10.
// ---------------------------------------------------------------------------

struct U2 { uint32_t a, b; };

// Threefry-2x32, 20 rounds, exactly as jax._src.prng
__device__ __forceinline__ U2 threefry(uint32_t k0, uint32_t k1, uint32_t x0, uint32_t x1) {
  const uint32_t ks2 = k0 ^ k1 ^ 0x1BD11BDAu;
#define TFR(r) { x0 += x1; x1 = (x1 << (r)) | (x1 >> (32 - (r))); x1 ^= x0; }
  x0 += k0;  x1 += k1;
  TFR(13) TFR(15) TFR(26) TFR(6)
  x0 += k1;  x1 += ks2 + 1u;
  TFR(17) TFR(29) TFR(16) TFR(24)
  x0 += ks2; x1 += k0 + 2u;
  TFR(13) TFR(15) TFR(26) TFR(6)
  x0 += k0;  x1 += k1 + 3u;
  TFR(17) TFR(29) TFR(16) TFR(24)
  x0 += k1;  x1 += ks2 + 4u;
  TFR(13) TFR(15) TFR(26) TFR(6)
  x0 += ks2; x1 += k0 + 5u;
#undef TFR
  U2 r; r.a = x0; r.b = x1; return r;
}

// partitionable random_bits, 32-bit: counter = flat index; fold o1^o2
__device__ __forceinline__ uint32_t pbits(uint32_t k0, uint32_t k1, uint32_t ctr) {
  U2 r = threefry(k0, k1, 0u, ctr);
  return r.a ^ r.b;
}

__device__ __forceinline__ float bits_to_unit(uint32_t bits) {
  return __uint_as_float((bits >> 9) | 0x3f800000u) - 1.0f;  // [0,1)
}

// f32 uniform(1e-6, 1-1e-6) -> gumbel, exactly jax's f32 path
__device__ __forceinline__ float jgumbel(uint32_t k0, uint32_t k1, uint32_t ctr) {
  const float minv = 1e-6f;
  const float maxv = (float)(1.0 - 1e-6);
  const float span = maxv - minv;
  float f = bits_to_unit(pbits(k0, k1, ctr));
  float u = fmaxf(minv, __fadd_rn(__fmul_rn(f, span), minv));
  return -logf(-logf(u));
}

extern "C" __global__ void __launch_bounds__(256)
gen_kernel(const float* __restrict__ noise,
           const float* __restrict__ w1,
           const float* __restrict__ b1,
           const float* __restrict__ gat_w,
           const float* __restrict__ gat_b,
           const float* __restrict__ w_atom,
           const float* __restrict__ b_atom,
           const float* __restrict__ w_hyb,
           const float* __restrict__ b_hyb,
           const float* __restrict__ w_deg,
           const float* __restrict__ b_deg,
           const float* __restrict__ w_chg,
           const float* __restrict__ b_chg,
           const float* __restrict__ w_arom,
           const float* __restrict__ b_arom,
           const float* __restrict__ w_eex,
           const float* __restrict__ b_eex,
           const float* __restrict__ w_ety,
           const float* __restrict__ b_ety,
           float* __restrict__ out)
{
  // All LDS regions are wave-private; no block barriers anywhere.
  // x layout: sX[wv][k] = {x_m0[k], x_m1[k]} -> k-loop reads are
  // uniform-address ds_read_b128 broadcasts.
  __shared__ __align__(16) double sX[4][128][2];   // 8 KB
  __shared__ double sScr[4][2][16];                // head logits, 1 KB
  __shared__ float  sNF[4][2][32][17];             // node features, 17.4 KB
  __shared__ double sLP[4][2][64];                 // lp scratch, 4 KB

  const int t       = threadIdx.x;
  const int wv      = t >> 6;
  const int ln      = t & 63;
  const int molPair = (blockIdx.x * 4 + wv) * 2;   // wave owns mols molPair, +1
  const int c0      = ln << 1;                     // lane's two columns

  // ---------------- stage noise for 2 molecules (wave-private)
  {
    const float2 n0 = *(const float2*)(noise + (size_t)molPair * 128 + c0);
    const float2 n1 = *(const float2*)(noise + (size_t)(molPair + 1) * 128 + c0);
    double2 v;
    v.x = (double)n0.x; v.y = (double)n1.x; *(double2*)&sX[wv][c0][0]     = v;
    v.x = (double)n0.y; v.y = (double)n1.y; *(double2*)&sX[wv][c0 + 1][0] = v;
  }

  double2 xr0, xr1;   // persistent per-lane x[c0],x[c0+1] per mol

  // ---------------- 17 unified layers:
  //   l==0 : x = relu(noise @ w1 + b1)
  //   l>=1 : x = relu(x + x@W_l + b_l)
  // Manual 2-stage software pipeline, chunks of 8 k-iterations (R10 shape).
  #pragma unroll 1
  for (int l = 0; l < 17; ++l) {
    const float* __restrict__ W  = (l == 0) ? w1 : (gat_w + (((size_t)(l - 1)) << 14));
    const float* __restrict__ bp = (l == 0) ? b1 : (gat_b + ((l - 1) << 7));

    double a0x = 0.0, a0y = 0.0, a1x = 0.0, a1y = 0.0;

    float2  wA[8];  double2 xA[8];
    float2  wB[8];  double2 xB[8];

    // prologue: chunk 0 -> buffer A
    #pragma unroll
    for (int j = 0; j < 8; ++j) {
      wA[j] = *(const float2*)(W + (j << 7) + c0);
      xA[j] = *(const double2*)&sX[wv][j][0];
    }

    #pragma unroll
    for (int ch = 0; ch < 16; ++ch) {
      const int nb = (ch + 1) << 3;                 // next chunk base
      if ((ch & 1) == 0) {
        if (ch < 15) {
          #pragma unroll
          for (int j = 0; j < 8; ++j) {
            wB[j] = *(const float2*)(W + ((nb + j) << 7) + c0);
            xB[j] = *(const double2*)&sX[wv][nb + j][0];
          }
        }
        #pragma unroll
        for (int j = 0; j < 8; ++j) {
          const double wx = (double)wA[j].x, wy = (double)wA[j].y;
          a0x = fma(xA[j].x, wx, a0x); a0y = fma(xA[j].x, wy, a0y);
          a1x = fma(xA[j].y, wx, a1x); a1y = fma(xA[j].y, wy, a1y);
        }
      } else {
        if (ch < 15) {
          #pragma unroll
          for (int j = 0; j < 8; ++j) {
            wA[j] = *(const float2*)(W + ((nb + j) << 7) + c0);
            xA[j] = *(const double2*)&sX[wv][nb + j][0];
          }
        }
        #pragma unroll
        for (int j = 0; j < 8; ++j) {
          const double wx = (double)wB[j].x, wy = (double)wB[j].y;
          a0x = fma(xB[j].x, wx, a0x); a0y = fma(xB[j].x, wy, a0y);
          a1x = fma(xB[j].y, wx, a1x); a1y = fma(xB[j].y, wy, a1y);
        }
      }
    }

    const float2 bb = *(const float2*)(bp + c0);
    const double bx = (double)bb.x, by = (double)bb.y;
    if (l == 0) {
      xr0.x = fmax(a0x + bx, 0.0); xr0.y = fmax(a0y + by, 0.0);
      xr1.x = fmax(a1x + bx, 0.0); xr1.y = fmax(a1y + by, 0.0);
    } else {
      xr0.x = fmax(xr0.x + a0x + bx, 0.0); xr0.y = fmax(xr0.y + a0y + by, 0.0);
      xr1.x = fmax(xr1.x + a1x + bx, 0.0); xr1.y = fmax(xr1.y + a1y + by, 0.0);
    }
    double2 v;
    v.x = xr0.x; v.y = xr1.x; *(double2*)&sX[wv][c0][0]     = v;
    v.x = xr0.y; v.y = xr1.y; *(double2*)&sX[wv][c0 + 1][0] = v;
  }

  // ---------------- phase A: head logits (lanes 0..31 = 2 mols x 16 heads)
  if (ln < 32) {
    const int mh = ln >> 4;            // 0..1
    const int h  = ln & 15;            // head index
    const double* xsrc = &sX[wv][0][mh];
    const float* wp; int stride; double bias;
    if (h < 10)       { wp = w_atom + h;        stride = 10; bias = (double)b_atom[h]; }
    else if (h < 13)  { wp = w_hyb + (h - 10);  stride = 3;  bias = (double)b_hyb[h - 10]; }
    else if (h == 13) { wp = w_deg;             stride = 1;  bias = (double)b_deg[0]; }
    else if (h == 14) { wp = w_chg;             stride = 1;  bias = (double)b_chg[0]; }
    else              { wp = w_arom;            stride = 1;  bias = (double)b_arom[0]; }
    double acc = 0.0;
    for (int c = 0; c < 128; ++c)
      acc = fma(xsrc[(size_t)c * 2], (double)wp[c * stride], acc);
    sScr[wv][mh][h] = acc + bias;
  }

  // partitionable split(key(42),4): child_i = threefry((0,42),(0,i))
  const U2 k0p = threefry(0u, 42u, 0u, 0u);
  const U2 k1p = threefry(0u, 42u, 0u, 1u);
  const U2 k2p = threefry(0u, 42u, 0u, 2u);
  const U2 k3p = threefry(0u, 42u, 0u, 3u);

  // ---------------- phase B: per-node sampling, 64 lanes = 2 mols x 32 nodes
  {
    const int mh  = ln >> 5;
    const int n   = ln & 31;
    const int mol = molPair + mh;
    const double* scr = sScr[wv][mh];     // same logits for every node

    double m = scr[0];
    #pragma unroll
    for (int a = 1; a < 10; ++a) m = fmax(m, scr[a]);
    double lsum = 0.0;
    #pragma unroll
    for (int a = 0; a < 10; ++a) lsum += exp(scr[a] - m);
    const double lse = log(lsum);
    const uint32_t abase = ((uint32_t)mol * 32u + (uint32_t)n) * 10u;
    int asel = 0; double abest = 0.0;
    #pragma unroll
    for (int a = 0; a < 10; ++a) {
      const double g = (double)jgumbel(k0p.a, k0p.b, abase + (uint32_t)a);
      const double sc = scr[a] + g;
      if (a == 0 || sc > abest) { abest = sc; asel = a; }
    }
    sLP[wv][mh][n] = (scr[asel] - m) - lse;

    double m2 = fmax(fmax(scr[10], scr[11]), scr[12]);
    double ls2 = exp(scr[10] - m2) + exp(scr[11] - m2) + exp(scr[12] - m2);
    const double lse2 = log(ls2);
    const uint32_t hbase = ((uint32_t)mol * 32u + (uint32_t)n) * 3u;
    int hsel = 0; double hbest = 0.0;
    #pragma unroll
    for (int j = 0; j < 3; ++j) {
      const double g = (double)jgumbel(k1p.a, k1p.b, hbase + (uint32_t)j);
      const double sc = scr[10 + j] + g;
      if (j == 0 || sc > hbest) { hbest = sc; hsel = j; }
    }
    sLP[wv][mh][32 + n] = (scr[10 + hsel] - m2) - lse2;

    const double deg = 1.0 / (1.0 + exp(-scr[13]));
    const double chg = tanh(scr[14]);
    const double pr  = 1.0 / (1.0 + exp(-scr[15]));
    const uint32_t ridx = (uint32_t)mol * 32u + (uint32_t)n;
    const double uu = (double)bits_to_unit(pbits(k2p.a, k2p.b, ridx));
    const double arom = (uu < pr) ? 1.0 : 0.0;
    const double valt[10] = {4.0/5.0, 3.0/5.0, 2.0/5.0, 1.0/5.0, 4.0/5.0,
                             2.0/5.0, 6.0/5.0, 1.0/5.0, 4.0/5.0, 4.0/5.0};
    double nf[17];
    #pragma unroll
    for (int i = 0; i < 10; ++i) nf[i] = (i == asel) ? 1.0 : 0.0;
    nf[10] = deg; nf[11] = chg;
    #pragma unroll
    for (int j = 0; j < 3; ++j) nf[12 + j] = (j == hsel) ? 1.0 : 0.0;
    nf[15] = arom; nf[16] = valt[asel];

    const size_t o = ((size_t)mol * 32 + n) * 17;
    #pragma unroll
    for (int i = 0; i < 17; ++i) {
      sNF[wv][mh][n][i] = (float)nf[i];
      out[o + i] = (float)nf[i];
    }
  }

  // ---------------- phase C: lp means + edge heads, 2 mols sequentially
  #pragma unroll 1
  for (int m = 0; m < 2; ++m) {
    const int mol = molPair + m;
    if (ln == 62) {
      double sa = 0.0;
      for (int n = 0; n < 32; ++n) sa += sLP[wv][m][n];
      out[2228224 + (size_t)mol] = (float)(sa / 32.0);
    } else if (ln == 63) {
      double sh = 0.0;
      for (int n = 0; n < 32; ++n) sh += sLP[wv][m][32 + n];
      out[2232320 + (size_t)mol] = (float)(sh / 32.0);
    } else {
      const int e = ln;                       // 0..61
      const int nu_ = (e < 31) ? e : (e - 30);
      const int nv_ = (e < 31) ? (e + 1) : (e - 31);
      double lex = 0.0;
      double lt[4] = {0.0, 0.0, 0.0, 0.0};
      for (int i = 0; i < 17; ++i) {
        const double f = (double)sNF[wv][m][nu_][i];
        lex = fma(f, (double)w_eex[i], lex);
        #pragma unroll
        for (int c = 0; c < 4; ++c) lt[c] = fma(f, (double)w_ety[i * 4 + c], lt[c]);
      }
      for (int i = 0; i < 17; ++i) {
        const double f = (double)sNF[wv][m][nv_][i];
        lex = fma(f, (double)w_eex[17 + i], lex);
        #pragma unroll
        for (int c = 0; c < 4; ++c) lt[c] = fma(f, (double)w_ety[(17 + i) * 4 + c], lt[c]);
      }
      lex += (double)b_eex[0];
      #pragma unroll
      for (int c = 0; c < 4; ++c) lt[c] += (double)b_ety[c];

      const double pex = 1.0 / (1.0 + exp(-lex));
      out[3252224 + (size_t)mol * 62 + e] = (pex > 0.5) ? 1.f : 0.f;

      const uint32_t tbase = ((uint32_t)mol * 62u + (uint32_t)e) * 4u;
      int tsel = 0; double tbest = 0.0;
      #pragma unroll
      for (int c = 0; c < 4; ++c) {
        const double g = (double)jgumbel(k3p.a, k3p.b, tbase + (uint32_t)c);
        const double sc = lt[c] + g;
        if (c == 0 || sc > tbest) { tbest = sc; tsel = c; }
      }
      const size_t o = 2236416 + ((size_t)mol * 62 + e) * 4;
      #pragma unroll
      for (int c = 0; c < 4; ++c) out[o + c] = (c == tsel) ? 1.f : 0.f;
    }
  }
}

extern "C" void kernel_launch(void* const* d_in, const int* in_sizes, int n_in,
                              void* d_out, int out_size, void* d_ws, size_t ws_size,
                              hipStream_t stream) {
  (void)in_sizes; (void)n_in; (void)out_size; (void)d_ws; (void)ws_size;
  hipLaunchKernelGGL(gen_kernel, dim3(512), dim3(256), 0, stream,
                     (const float*)d_in[0],  (const float*)d_in[1],
                     (const float*)d_in[2],  (const float*)d_in[3],
                     (const float*)d_in[4],
                     (const float*)d_in[7],  (const float*)d_in[8],
                     (const float*)d_in[9],  (const float*)d_in[10],
                     (const float*)d_in[11], (const float*)d_in[12],
                     (const float*)d_in[13], (const float*)d_in[14],
                     (const float*)d_in[15], (const float*)d_in[16],
                     (const float*)d_in[17], (const float*)d_in[18],
                     (const float*)d_in[19], (const float*)d_in[20],
                     (float*)d_out);
}

// Round 8
// 217.290 us; speedup vs baseline: 7.4624x; 1.1374x over previous
//
#include <hip/hip_runtime.h>
#include <stdint.h>
#include <math.h>

// ---------------------------------------------------------------------------
// Generator_44555990728950. B=4096 molecules, N=32 nodes (chain), H=128,
// 16 GAT layers. All 32 nodes of a molecule are identical through the GAT
// stack (broadcast init + attention weights sum to 1 over identical
// neighbors), so: layer = relu(x + x@W + b), one class per molecule.
// R14: REGISTER-RESIDENT x + v_readlane broadcast; zero LDS in main loop.
//   R9-R13 post-mortem: all LDS-broadcast variants share a fixed cost --
//   4.45M uniform ds_read_b128 / 256 CU = 17.4k reads x ~12cyc = ~87us on
//   the per-CU DS pipe (shared by 4 SIMDs), invariant in M and occupancy.
//   Fix: x stays in VGPRs (lane ln owns cols 2ln,2ln+1); broadcast x[k] via
//   __builtin_amdgcn_readlane (lane=k>>1, comp=k&1, compile-time after
//   unroll) -> wave-uniform SGPR-pair feeds v_fma_f64 directly. Moves the
//   broadcast to the per-SIMD VALU pipe (4x throughput): ~56cyc/iter x 2176
//   = ~51us VALU-bound. W loads keep the 2-stage chunk pipeline (only
//   float2[8] x2 buffers -> no spill pressure). M=4, 256 blocks x 256 thr,
//   1 block/CU, barrier-free, plain __launch_bounds__(256) (R10 regime).
// Deterministic pipeline fp64 (accumulation order unchanged); JAX
// partitionable threefry bit-exact; outputs fp32.
// ---------------------------------------------------------------------------

struct U2 { uint32_t a, b; };

// Threefry-2x32, 20 rounds, exactly as jax._src.prng
__device__ __forceinline__ U2 threefry(uint32_t k0, uint32_t k1, uint32_t x0, uint32_t x1) {
  const uint32_t ks2 = k0 ^ k1 ^ 0x1BD11BDAu;
#define TFR(r) { x0 += x1; x1 = (x1 << (r)) | (x1 >> (32 - (r))); x1 ^= x0; }
  x0 += k0;  x1 += k1;
  TFR(13) TFR(15) TFR(26) TFR(6)
  x0 += k1;  x1 += ks2 + 1u;
  TFR(17) TFR(29) TFR(16) TFR(24)
  x0 += ks2; x1 += k0 + 2u;
  TFR(13) TFR(15) TFR(26) TFR(6)
  x0 += k0;  x1 += k1 + 3u;
  TFR(17) TFR(29) TFR(16) TFR(24)
  x0 += k1;  x1 += ks2 + 4u;
  TFR(13) TFR(15) TFR(26) TFR(6)
  x0 += ks2; x1 += k0 + 5u;
#undef TFR
  U2 r; r.a = x0; r.b = x1; return r;
}

// partitionable random_bits, 32-bit: counter = flat index; fold o1^o2
__device__ __forceinline__ uint32_t pbits(uint32_t k0, uint32_t k1, uint32_t ctr) {
  U2 r = threefry(k0, k1, 0u, ctr);
  return r.a ^ r.b;
}

__device__ __forceinline__ float bits_to_unit(uint32_t bits) {
  return __uint_as_float((bits >> 9) | 0x3f800000u) - 1.0f;  // [0,1)
}

// f32 uniform(1e-6, 1-1e-6) -> gumbel, exactly jax's f32 path
__device__ __forceinline__ float jgumbel(uint32_t k0, uint32_t k1, uint32_t ctr) {
  const float minv = 1e-6f;
  const float maxv = (float)(1.0 - 1e-6);
  const float span = maxv - minv;
  float f = bits_to_unit(pbits(k0, k1, ctr));
  float u = fmaxf(minv, __fadd_rn(__fmul_rn(f, span), minv));
  return -logf(-logf(u));
}

// wave-broadcast a double from a given lane (compile-time lane after unroll)
__device__ __forceinline__ double rl_bcast(double v, int lane) {
  union { double d; unsigned int u[2]; } c; c.d = v;
  unsigned int lo = __builtin_amdgcn_readlane(c.u[0], lane);
  unsigned int hi = __builtin_amdgcn_readlane(c.u[1], lane);
  union { double d; unsigned int u[2]; } r; r.u[0] = lo; r.u[1] = hi;
  return r.d;
}

extern "C" __global__ void __launch_bounds__(256)
gen_kernel(const float* __restrict__ noise,
           const float* __restrict__ w1,
           const float* __restrict__ b1,
           const float* __restrict__ gat_w,
           const float* __restrict__ gat_b,
           const float* __restrict__ w_atom,
           const float* __restrict__ b_atom,
           const float* __restrict__ w_hyb,
           const float* __restrict__ b_hyb,
           const float* __restrict__ w_deg,
           const float* __restrict__ b_deg,
           const float* __restrict__ w_chg,
           const float* __restrict__ b_chg,
           const float* __restrict__ w_arom,
           const float* __restrict__ b_arom,
           const float* __restrict__ w_eex,
           const float* __restrict__ b_eex,
           const float* __restrict__ w_ety,
           const float* __restrict__ b_ety,
           float* __restrict__ out)
{
  // LDS used ONLY by the head/sampling phases (wave-private, no barriers).
  __shared__ __align__(16) double sX[4][128][4];   // x after 17 layers, 16 KB
  __shared__ double sScr[4][4][16];                // head logits, 2 KB
  __shared__ float  sNF[4][4][32][17];             // node features, 34.8 KB
  __shared__ double sLP[4][4][64];                 // lp scratch, 8 KB

  const int t       = threadIdx.x;
  const int wv      = t >> 6;
  const int ln      = t & 63;
  const int molBase = blockIdx.x * 16 + wv * 4;    // wave owns mols molBase..+3
  const int c0      = ln << 1;                     // lane's two columns

  // x state entirely in registers: xm = {x[c0], x[c0+1]} per mol
  double2 x0, x1, x2, x3;

  // ---------------- stage noise directly into x registers
  {
    const float2 n0 = *(const float2*)(noise + (size_t)(molBase + 0) * 128 + c0);
    const float2 n1 = *(const float2*)(noise + (size_t)(molBase + 1) * 128 + c0);
    const float2 n2 = *(const float2*)(noise + (size_t)(molBase + 2) * 128 + c0);
    const float2 n3 = *(const float2*)(noise + (size_t)(molBase + 3) * 128 + c0);
    x0.x = (double)n0.x; x0.y = (double)n0.y;
    x1.x = (double)n1.x; x1.y = (double)n1.y;
    x2.x = (double)n2.x; x2.y = (double)n2.y;
    x3.x = (double)n3.x; x3.y = (double)n3.y;
  }

  // ---------------- 17 unified layers:
  //   l==0 : x = relu(noise @ w1 + b1)        (input = x regs, no residual)
  //   l>=1 : x = relu(x + x@W_l + b_l)
  // W loads: 2-stage pipeline, chunks of 8 k-iters. x broadcast: readlane.
  #pragma unroll 1
  for (int l = 0; l < 17; ++l) {
    const float* __restrict__ W  = (l == 0) ? w1 : (gat_w + (((size_t)(l - 1)) << 14));
    const float* __restrict__ bp = (l == 0) ? b1 : (gat_b + ((l - 1) << 7));

    double a0x = 0.0, a0y = 0.0, a1x = 0.0, a1y = 0.0;
    double a2x = 0.0, a2y = 0.0, a3x = 0.0, a3y = 0.0;

    float2 wA[8], wB[8];

    // prologue: chunk 0 -> buffer A
    #pragma unroll
    for (int j = 0; j < 8; ++j)
      wA[j] = *(const float2*)(W + (j << 7) + c0);

    #pragma unroll
    for (int ch = 0; ch < 16; ++ch) {
      const int nb = (ch + 1) << 3;                 // next chunk base (compile-time)
      if ((ch & 1) == 0) {
        if (ch < 15) {
          #pragma unroll
          for (int j = 0; j < 8; ++j)
            wB[j] = *(const float2*)(W + ((nb + j) << 7) + c0);
        }
        #pragma unroll
        for (int j = 0; j < 8; ++j) {
          const int k    = (ch << 3) + j;           // compile-time
          const int lane = k >> 1;
          const double xa0 = rl_bcast((k & 1) ? x0.y : x0.x, lane);
          const double xa1 = rl_bcast((k & 1) ? x1.y : x1.x, lane);
          const double xa2 = rl_bcast((k & 1) ? x2.y : x2.x, lane);
          const double xa3 = rl_bcast((k & 1) ? x3.y : x3.x, lane);
          const double wx = (double)wA[j].x, wy = (double)wA[j].y;
          a0x = fma(xa0, wx, a0x); a0y = fma(xa0, wy, a0y);
          a1x = fma(xa1, wx, a1x); a1y = fma(xa1, wy, a1y);
          a2x = fma(xa2, wx, a2x); a2y = fma(xa2, wy, a2y);
          a3x = fma(xa3, wx, a3x); a3y = fma(xa3, wy, a3y);
        }
      } else {
        if (ch < 15) {
          #pragma unroll
          for (int j = 0; j < 8; ++j)
            wA[j] = *(const float2*)(W + ((nb + j) << 7) + c0);
        }
        #pragma unroll
        for (int j = 0; j < 8; ++j) {
          const int k    = (ch << 3) + j;           // compile-time
          const int lane = k >> 1;
          const double xa0 = rl_bcast((k & 1) ? x0.y : x0.x, lane);
          const double xa1 = rl_bcast((k & 1) ? x1.y : x1.x, lane);
          const double xa2 = rl_bcast((k & 1) ? x2.y : x2.x, lane);
          const double xa3 = rl_bcast((k & 1) ? x3.y : x3.x, lane);
          const double wx = (double)wB[j].x, wy = (double)wB[j].y;
          a0x = fma(xa0, wx, a0x); a0y = fma(xa0, wy, a0y);
          a1x = fma(xa1, wx, a1x); a1y = fma(xa1, wy, a1y);
          a2x = fma(xa2, wx, a2x); a2y = fma(xa2, wy, a2y);
          a3x = fma(xa3, wx, a3x); a3y = fma(xa3, wy, a3y);
        }
      }
    }

    const float2 bb = *(const float2*)(bp + c0);
    const double bx = (double)bb.x, by = (double)bb.y;
    if (l == 0) {
      x0.x = fmax(a0x + bx, 0.0); x0.y = fmax(a0y + by, 0.0);
      x1.x = fmax(a1x + bx, 0.0); x1.y = fmax(a1y + by, 0.0);
      x2.x = fmax(a2x + bx, 0.0); x2.y = fmax(a2y + by, 0.0);
      x3.x = fmax(a3x + bx, 0.0); x3.y = fmax(a3y + by, 0.0);
    } else {
      x0.x = fmax(x0.x + a0x + bx, 0.0); x0.y = fmax(x0.y + a0y + by, 0.0);
      x1.x = fmax(x1.x + a1x + bx, 0.0); x1.y = fmax(x1.y + a1y + by, 0.0);
      x2.x = fmax(x2.x + a2x + bx, 0.0); x2.y = fmax(x2.y + a2y + by, 0.0);
      x3.x = fmax(x3.x + a3x + bx, 0.0); x3.y = fmax(x3.y + a3y + by, 0.0);
    }
  }

  // ---------------- publish x to LDS for the head phases (wave-private)
  {
    double2 v;
    v.x = x0.x; v.y = x1.x; *(double2*)&sX[wv][c0][0]     = v;
    v.x = x2.x; v.y = x3.x; *(double2*)&sX[wv][c0][2]     = v;
    v.x = x0.y; v.y = x1.y; *(double2*)&sX[wv][c0 + 1][0] = v;
    v.x = x2.y; v.y = x3.y; *(double2*)&sX[wv][c0 + 1][2] = v;
  }

  // ---------------- phase A: head logits, all 64 lanes = 4 mols x 16 heads
  {
    const int mloc = ln >> 4;          // 0..3
    const int h    = ln & 15;          // head index
    const double* xsrc = &sX[wv][0][mloc];
    const float* wp; int stride; double bias;
    if (h < 10)       { wp = w_atom + h;        stride = 10; bias = (double)b_atom[h]; }
    else if (h < 13)  { wp = w_hyb + (h - 10);  stride = 3;  bias = (double)b_hyb[h - 10]; }
    else if (h == 13) { wp = w_deg;             stride = 1;  bias = (double)b_deg[0]; }
    else if (h == 14) { wp = w_chg;             stride = 1;  bias = (double)b_chg[0]; }
    else              { wp = w_arom;            stride = 1;  bias = (double)b_arom[0]; }
    double acc = 0.0;
    for (int c = 0; c < 128; ++c)
      acc = fma(xsrc[(size_t)c * 4], (double)wp[c * stride], acc);
    sScr[wv][mloc][h] = acc + bias;
  }

  // partitionable split(key(42),4): child_i = threefry((0,42),(0,i))
  const U2 k0p = threefry(0u, 42u, 0u, 0u);
  const U2 k1p = threefry(0u, 42u, 0u, 1u);
  const U2 k2p = threefry(0u, 42u, 0u, 2u);
  const U2 k3p = threefry(0u, 42u, 0u, 3u);

  // ---------------- phase B: per-node sampling, 2 rounds of (2 mols x 32 nodes)
  for (int r = 0; r < 2; ++r) {
    const int mloc = r * 2 + (ln >> 5);
    const int n    = ln & 31;
    const int mol  = molBase + mloc;
    const double* scr = sScr[wv][mloc];   // same logits for every node

    double m = scr[0];
    #pragma unroll
    for (int a = 1; a < 10; ++a) m = fmax(m, scr[a]);
    double lsum = 0.0;
    #pragma unroll
    for (int a = 0; a < 10; ++a) lsum += exp(scr[a] - m);
    const double lse = log(lsum);
    const uint32_t abase = ((uint32_t)mol * 32u + (uint32_t)n) * 10u;
    int asel = 0; double abest = 0.0;
    #pragma unroll
    for (int a = 0; a < 10; ++a) {
      const double g = (double)jgumbel(k0p.a, k0p.b, abase + (uint32_t)a);
      const double sc = scr[a] + g;
      if (a == 0 || sc > abest) { abest = sc; asel = a; }
    }
    sLP[wv][mloc][n] = (scr[asel] - m) - lse;

    double m2 = fmax(fmax(scr[10], scr[11]), scr[12]);
    double ls2 = exp(scr[10] - m2) + exp(scr[11] - m2) + exp(scr[12] - m2);
    const double lse2 = log(ls2);
    const uint32_t hbase = ((uint32_t)mol * 32u + (uint32_t)n) * 3u;
    int hsel = 0; double hbest = 0.0;
    #pragma unroll
    for (int j = 0; j < 3; ++j) {
      const double g = (double)jgumbel(k1p.a, k1p.b, hbase + (uint32_t)j);
      const double sc = scr[10 + j] + g;
      if (j == 0 || sc > hbest) { hbest = sc; hsel = j; }
    }
    sLP[wv][mloc][32 + n] = (scr[10 + hsel] - m2) - lse2;

    const double deg = 1.0 / (1.0 + exp(-scr[13]));
    const double chg = tanh(scr[14]);
    const double pr  = 1.0 / (1.0 + exp(-scr[15]));
    const uint32_t ridx = (uint32_t)mol * 32u + (uint32_t)n;
    const double uu = (double)bits_to_unit(pbits(k2p.a, k2p.b, ridx));
    const double arom = (uu < pr) ? 1.0 : 0.0;
    const double valt[10] = {4.0/5.0, 3.0/5.0, 2.0/5.0, 1.0/5.0, 4.0/5.0,
                             2.0/5.0, 6.0/5.0, 1.0/5.0, 4.0/5.0, 4.0/5.0};
    double nf[17];
    #pragma unroll
    for (int i = 0; i < 10; ++i) nf[i] = (i == asel) ? 1.0 : 0.0;
    nf[10] = deg; nf[11] = chg;
    #pragma unroll
    for (int j = 0; j < 3; ++j) nf[12 + j] = (j == hsel) ? 1.0 : 0.0;
    nf[15] = arom; nf[16] = valt[asel];

    const size_t o = ((size_t)mol * 32 + n) * 17;
    #pragma unroll
    for (int i = 0; i < 17; ++i) {
      sNF[wv][mloc][n][i] = (float)nf[i];
      out[o + i] = (float)nf[i];
    }
  }

  // ---------------- phase C: lp means + edge heads, 4 mols sequentially
  #pragma unroll 1
  for (int m = 0; m < 4; ++m) {
    const int mol = molBase + m;
    if (ln == 62) {
      double sa = 0.0;
      for (int n = 0; n < 32; ++n) sa += sLP[wv][m][n];
      out[2228224 + (size_t)mol] = (float)(sa / 32.0);
    } else if (ln == 63) {
      double sh = 0.0;
      for (int n = 0; n < 32; ++n) sh += sLP[wv][m][32 + n];
      out[2232320 + (size_t)mol] = (float)(sh / 32.0);
    } else {
      const int e = ln;                       // 0..61
      const int nu_ = (e < 31) ? e : (e - 30);
      const int nv_ = (e < 31) ? (e + 1) : (e - 31);
      double lex = 0.0;
      double lt[4] = {0.0, 0.0, 0.0, 0.0};
      for (int i = 0; i < 17; ++i) {
        const double f = (double)sNF[wv][m][nu_][i];
        lex = fma(f, (double)w_eex[i], lex);
        #pragma unroll
        for (int c = 0; c < 4; ++c) lt[c] = fma(f, (double)w_ety[i * 4 + c], lt[c]);
      }
      for (int i = 0; i < 17; ++i) {
        const double f = (double)sNF[wv][m][nv_][i];
        lex = fma(f, (double)w_eex[17 + i], lex);
        #pragma unroll
        for (int c = 0; c < 4; ++c) lt[c] = fma(f, (double)w_ety[(17 + i) * 4 + c], lt[c]);
      }
      lex += (double)b_eex[0];
      #pragma unroll
      for (int c = 0; c < 4; ++c) lt[c] += (double)b_ety[c];

      const double pex = 1.0 / (1.0 + exp(-lex));
      out[3252224 + (size_t)mol * 62 + e] = (pex > 0.5) ? 1.f : 0.f;

      const uint32_t tbase = ((uint32_t)mol * 62u + (uint32_t)e) * 4u;
      int tsel = 0; double tbest = 0.0;
      #pragma unroll
      for (int c = 0; c < 4; ++c) {
        const double g = (double)jgumbel(k3p.a, k3p.b, tbase + (uint32_t)c);
        const double sc = lt[c] + g;
        if (c == 0 || sc > tbest) { tbest = sc; tsel = c; }
      }
      const size_t o = 2236416 + ((size_t)mol * 62 + e) * 4;
      #pragma unroll
      for (int c = 0; c < 4; ++c) out[o + c] = (c == tsel) ? 1.f : 0.f;
    }
  }
}

extern "C" void kernel_launch(void* const* d_in, const int* in_sizes, int n_in,
                              void* d_out, int out_size, void* d_ws, size_t ws_size,
                              hipStream_t stream) {
  (void)in_sizes; (void)n_in; (void)out_size; (void)d_ws; (void)ws_size;
  hipLaunchKernelGGL(gen_kernel, dim3(256), dim3(256), 0, stream,
                     (const float*)d_in[0],  (const float*)d_in[1],
                     (const float*)d_in[2],  (const float*)d_in[3],
                     (const float*)d_in[4],
                     (const float*)d_in[7],  (const float*)d_in[8],
                     (const float*)d_in[9],  (const float*)d_in[10],
                     (const float*)d_in[11], (const float*)d_in[12],
                     (const float*)d_in[13], (const float*)d_in[14],
                     (const float*)d_in[15], (const float*)d_in[16],
                     (const float*)d_in[17], (const float*)d_in[18],
                     (const float*)d_in[19], (const float*)d_in[20],
                     (float*)d_out);
}